// Round 1
// 1070.377 us; speedup vs baseline: 1.6312x; 1.6312x over previous
//
#include <hip/hip_runtime.h>
#include <math.h>

// Problem constants (CollaborativeRNNModel): B=32, S=128, U=256, H=128, V=30001
#define B_    32
#define S_    128
#define U_    256
#define H_    128
#define H2_   256
#define V_    30001
#define ROWS_ 4096   // B_*S_

// Split-bf16 GEMM geometry: K' = 3*128 (A_hi*B_hi + A_lo*B_hi + A_hi*B_lo)
#define KP_    384
#define NK32_  12            // KP_/32 k-subtiles
#define NR16_  256           // ROWS_/16 row tiles
#define NCB_   235           // ceil(30001/128) col block-tiles
#define NC16_  1880          // NCB_*8 col 16-tiles (padded N = 30080)

typedef __attribute__((ext_vector_type(8))) short  short8;  // 8 bf16 = 4 VGPRs
typedef __attribute__((ext_vector_type(4))) float  f32x4;

static __device__ __forceinline__ unsigned short f2bf(float x) {
    // round-to-nearest-even fp32 -> bf16
    unsigned int u = __float_as_uint(x);
    unsigned int r = (u + 0x7fffu + ((u >> 16) & 1u)) >> 16;
    return (unsigned short)r;
}
static __device__ __forceinline__ float bf2f(unsigned short h) {
    return __uint_as_float(((unsigned int)h) << 16);
}

// ---------------------------------------------------------------------------
// Kernel 1: per-batch GRU-like recurrence (UNCHANGED from previous round).
// Writes activations TRANSPOSED: At[j][b*S+t]  (k-major).
// ---------------------------------------------------------------------------
__global__ __launch_bounds__(256) void rnn_kernel(
    const int*   __restrict__ users, const int* __restrict__ items,
    const float* __restrict__ h0,
    const float* __restrict__ P_ru, const float* __restrict__ W_ru,
    const float* __restrict__ b_ru,
    const float* __restrict__ P_c,  const float* __restrict__ W_c,
    const float* __restrict__ b_c,
    float* __restrict__ At)          // [H_][ROWS_]
{
    __shared__ float state[U_ * H_];   // 128 KiB
    __shared__ float rbuf[H_];
    __shared__ float zbuf[H_];
    __shared__ int   us[S_];
    __shared__ int   is[S_];

    const int b   = blockIdx.x;
    const int tid = threadIdx.x;

    {
        const float4* src = (const float4*)(h0 + (size_t)b * U_ * H_);
        float4*       dst = (float4*)state;
        #pragma unroll
        for (int i = 0; i < (U_ * H_ / 4) / 256; ++i)
            dst[i * 256 + tid] = src[i * 256 + tid];
    }
    if (tid < S_) {
        us[tid] = users[b * S_ + tid];
        is[tid] = items[b * S_ + tid];
    }
    const float brj = b_ru[tid];
    const float bcj = (tid < H_) ? b_c[tid] : 0.f;
    __syncthreads();

    for (int t = 0; t < S_; ++t) {
        const int u  = us[t];
        const int it = is[t];
        const float* hrow = state + u * H_;

        const float p = P_ru[(size_t)it * H2_ + tid];

        float acc = 0.f;
        const float* wcol = W_ru + tid;
        #pragma unroll 8
        for (int k4 = 0; k4 < H_; k4 += 4) {
            const float4 hv = *((const float4*)(hrow + k4));
            acc = fmaf(hv.x, wcol[(k4 + 0) * H2_], acc);
            acc = fmaf(hv.y, wcol[(k4 + 1) * H2_], acc);
            acc = fmaf(hv.z, wcol[(k4 + 2) * H2_], acc);
            acc = fmaf(hv.w, wcol[(k4 + 3) * H2_], acc);
        }
        acc += p + brj;
        const float sg = 1.f / (1.f + expf(-acc));
        if (tid < H_) rbuf[tid] = sg * hrow[tid];
        else          zbuf[tid - H_] = sg;
        __syncthreads();

        if (tid < H_) {
            const float pc = P_c[(size_t)it * H_ + tid];
            float acc2 = 0.f;
            const float* wccol = W_c + tid;
            #pragma unroll 8
            for (int k4 = 0; k4 < H_; k4 += 4) {
                const float4 rv = *((const float4*)(rbuf + k4));
                acc2 = fmaf(rv.x, wccol[(k4 + 0) * H_], acc2);
                acc2 = fmaf(rv.y, wccol[(k4 + 1) * H_], acc2);
                acc2 = fmaf(rv.z, wccol[(k4 + 2) * H_], acc2);
                acc2 = fmaf(rv.w, wccol[(k4 + 3) * H_], acc2);
            }
            acc2 += pc + bcj;
            const float c  = tanhf(acc2);
            const float z  = zbuf[tid];
            const float hp = hrow[tid];
            const float hn = fmaf(z, hp - c, c);
            state[u * H_ + tid] = hn;
            At[(size_t)tid * ROWS_ + b * S_ + t] = hn;
        }
        __syncthreads();
    }
}

// ---------------------------------------------------------------------------
// Kernel 2a: pack A' = [A_hi | A_lo | A_hi] (k' = 0..383) into MFMA fragment
// order: Ap[k32][r16][lane][j] bf16, where lane l of tile (r16,k32) holds
// A[r16*16 + (l&15)][(k32&3)*32 + (l>>4)*8 + j].  Part p = k32>>2: 0,2 -> hi,
// 1 -> lo.  Total 12*256*512 bf16 = 3 MiB.
// One thread per (tile,lane): reads 8 fp32 from At, writes one 16B fragment.
// ---------------------------------------------------------------------------
__global__ __launch_bounds__(256) void convA_kernel(
    const float* __restrict__ At, short* __restrict__ Ap)
{
    const int gidx = blockIdx.x * 256 + threadIdx.x;   // [0, 12*256*64)
    const int lane = gidx & 63;
    const int tile = gidx >> 6;        // k32*256 + r16
    const int k32  = tile >> 8;
    const int r16  = tile & 255;
    const int part = k32 >> 2;
    const int ks   = (k32 & 3) * 32 + (lane >> 4) * 8;  // source k in [0,128)
    const int row  = r16 * 16 + (lane & 15);
    short8 v;
    #pragma unroll
    for (int j = 0; j < 8; ++j) {
        const float x = At[(size_t)(ks + j) * ROWS_ + row];
        const unsigned short hi = f2bf(x);
        v[j] = (short)((part == 1) ? f2bf(x - bf2f(hi)) : hi);
    }
    *(short8*)(Ap + (size_t)gidx * 8) = v;
}

// ---------------------------------------------------------------------------
// Kernel 2b: pack B' = [B_hi ; B_hi ; B_lo] (k' = 0..383) the same way:
// Bp[k32][c16][lane][j], lane l of tile (c16,k32) holds
// ws[(k32&3)*32 + (l>>4)*8 + j][c16*16 + (l&15)].  Part 0,1 -> hi, 2 -> lo.
// Cols >= 30001 zero-padded.  Total 12*1880*512 bf16 = 22 MiB.
// ---------------------------------------------------------------------------
__global__ __launch_bounds__(256) void convB_kernel(
    const float* __restrict__ wsm, short* __restrict__ Bp)
{
    const int gidx = blockIdx.x * 256 + threadIdx.x;   // [0, 12*1880*64)
    const int lane = gidx & 63;
    const int tile = gidx >> 6;        // k32*1880 + c16
    const int k32  = tile / NC16_;
    const int c16  = tile - k32 * NC16_;
    const int part = k32 >> 2;
    const int ks   = (k32 & 3) * 32 + (lane >> 4) * 8;
    const int col  = c16 * 16 + (lane & 15);
    short8 v;
    if (col < V_) {
        #pragma unroll
        for (int j = 0; j < 8; ++j) {
            const float x = wsm[(size_t)(ks + j) * V_ + col];
            const unsigned short hi = f2bf(x);
            v[j] = (short)((part == 2) ? f2bf(x - bf2f(hi)) : hi);
        }
    } else {
        #pragma unroll
        for (int j = 0; j < 8; ++j) v[j] = 0;
    }
    *(short8*)(Bp + (size_t)gidx * 8) = v;
}

// ---------------------------------------------------------------------------
// Kernel 3: MFMA GEMM  out[4096][30001] = A'[4096][384] @ B'[384][30001].
// m97-structure: 128x128 block tile, 4 waves (2x2), each wave 64x64 = 4x4
// fragments of 16x16x32 bf16.  BK=64 per stage (2 k32 subtiles), LDS 32 KiB
// single-buffered.  Staging is a LINEAR global_load_lds dwordx4 copy (global
// layout is pre-swizzled to fragment order), fragment reads are single
// conflict-free ds_read_b128 (lane-contiguous 16B).
// ---------------------------------------------------------------------------
__global__ __launch_bounds__(256) void gemm_mfma_kernel(
    const short* __restrict__ Ap, const short* __restrict__ Bp,
    float* __restrict__ out)
{
    __shared__ short lsA[2][4096];   // [k32 sub][8 r16-tiles][64 lanes][8]
    __shared__ short lsB[2][4096];   // [k32 sub][8 c16-tiles][64 lanes][8]

    const int tid  = threadIdx.x;
    const int lane = tid & 63;
    const int wid  = tid >> 6;
    const int wr   = wid >> 1;       // wave row 0..1 (64-row slab)
    const int wc   = wid & 1;        // wave col 0..1 (64-col slab)
    const int rb16 = blockIdx.x * 8; // base row-16-tile
    const int cb16 = blockIdx.y * 8; // base col-16-tile

    const f32x4 zero = {0.f, 0.f, 0.f, 0.f};
    f32x4 acc[4][4];
    #pragma unroll
    for (int m = 0; m < 4; ++m)
        #pragma unroll
        for (int n = 0; n < 4; ++n) acc[m][n] = zero;

    for (int kk = 0; kk < 6; ++kk) {
        // stage k32 = 2kk, 2kk+1 : 16 KiB A + 16 KiB B, pure linear copy
        #pragma unroll
        for (int s = 0; s < 2; ++s) {
            const int k32 = kk * 2 + s;
            const short* ga = Ap + ((size_t)k32 * NR16_ + rb16) * 512;
            const short* gb = Bp + ((size_t)k32 * NC16_ + cb16) * 512;
            #pragma unroll
            for (int i = 0; i < 2; ++i) {
                const int idx = (i * 256 + tid) * 8;   // 8 shorts = 16B per thread
                __builtin_amdgcn_global_load_lds(
                    (__attribute__((address_space(1))) void*)(ga + idx),
                    (__attribute__((address_space(3))) void*)(&lsA[s][idx]), 16, 0, 0);
                __builtin_amdgcn_global_load_lds(
                    (__attribute__((address_space(1))) void*)(gb + idx),
                    (__attribute__((address_space(3))) void*)(&lsB[s][idx]), 16, 0, 0);
            }
        }
        __syncthreads();   // drains vmcnt before use

        #pragma unroll
        for (int s = 0; s < 2; ++s) {
            short8 a[4], b[4];
            #pragma unroll
            for (int m = 0; m < 4; ++m)
                a[m] = *(const short8*)&lsA[s][((wr * 4 + m) * 64 + lane) * 8];
            #pragma unroll
            for (int n = 0; n < 4; ++n)
                b[n] = *(const short8*)&lsB[s][((wc * 4 + n) * 64 + lane) * 8];
            #pragma unroll
            for (int m = 0; m < 4; ++m)
                #pragma unroll
                for (int n = 0; n < 4; ++n)
                    acc[m][n] = __builtin_amdgcn_mfma_f32_16x16x32_bf16(
                        a[m], b[n], acc[m][n], 0, 0, 0);
        }
        __syncthreads();   // LDS reuse next stage
    }

    // Epilogue: C/D layout col = lane&15, row = (lane>>4)*4 + reg  [HW-verified]
    const int row0 = blockIdx.x * 128 + wr * 64 + ((lane >> 4) << 2);
    const int col0 = blockIdx.y * 128 + wc * 64 + (lane & 15);
    #pragma unroll
    for (int m = 0; m < 4; ++m) {
        #pragma unroll
        for (int n = 0; n < 4; ++n) {
            const int col = col0 + n * 16;
            if (col < V_) {
                float* o = out + (size_t)(row0 + m * 16) * V_ + col;
                o[0]              = acc[m][n][0];
                o[(size_t)V_]     = acc[m][n][1];
                o[(size_t)V_ * 2] = acc[m][n][2];
                o[(size_t)V_ * 3] = acc[m][n][3];
            }
        }
    }
}

extern "C" void kernel_launch(void* const* d_in, const int* in_sizes, int n_in,
                              void* d_out, int out_size, void* d_ws, size_t ws_size,
                              hipStream_t stream) {
    const int*   users = (const int*)  d_in[0];
    const int*   items = (const int*)  d_in[1];
    const float* h0    = (const float*)d_in[2];
    const float* P_ru  = (const float*)d_in[3];
    const float* W_ru  = (const float*)d_in[4];
    const float* b_ru  = (const float*)d_in[5];
    const float* P_c   = (const float*)d_in[6];
    const float* W_c   = (const float*)d_in[7];
    const float* b_c   = (const float*)d_in[8];
    const float* wsm   = (const float*)d_in[9];
    float* out = (float*)d_out;

    // workspace layout: At (2 MiB fp32) | Ap (3 MiB bf16) | Bp (22 MiB bf16)
    float* At = (float*)d_ws;                                        // [128][4096]
    short* Ap = (short*)((char*)d_ws + (size_t)2 * 1024 * 1024);     // 12*256*512
    short* Bp = (short*)((char*)d_ws + (size_t)2 * 1024 * 1024
                                     + (size_t)NK32_ * NR16_ * 512 * sizeof(short));

    rnn_kernel<<<B_, 256, 0, stream>>>(users, items, h0, P_ru, W_ru, b_ru,
                                       P_c, W_c, b_c, At);
    convA_kernel<<<(NK32_ * NR16_ * 64) / 256, 256, 0, stream>>>(At, Ap);
    convB_kernel<<<(NK32_ * NC16_ * 64) / 256, 256, 0, stream>>>(wsm, Bp);
    gemm_mfma_kernel<<<dim3(32, NCB_), 256, 0, stream>>>(Ap, Bp, out);
}

// Round 2
// 813.649 us; speedup vs baseline: 2.1459x; 1.3155x over previous
//
#include <hip/hip_runtime.h>
#include <math.h>

// Problem constants (CollaborativeRNNModel): B=32, S=128, U=256, H=128, V=30001
#define B_    32
#define S_    128
#define U_    256
#define H_    128
#define H2_   256
#define V_    30001
#define ROWS_ 4096   // B_*S_
#define CH_   16     // steps per chunk in the level-parallel RNN

// Split-bf16 GEMM geometry: K' = 3*128 (A_hi*B_hi + A_lo*B_hi + A_hi*B_lo)
#define KP_    384
#define NK32_  12            // KP_/32 k-subtiles
#define NR16_  256           // ROWS_/16 row tiles
#define NCB_   235           // ceil(30001/128) col block-tiles
#define NC16_  1880          // NCB_*8 col 16-tiles (padded N = 30080)

typedef __attribute__((ext_vector_type(8))) short  short8;  // 8 bf16 = 4 VGPRs
typedef __attribute__((ext_vector_type(4))) float  f32x4;

static __device__ __forceinline__ unsigned short f2bf(float x) {
    unsigned int u = __float_as_uint(x);
    unsigned int r = (u + 0x7fffu + ((u >> 16) & 1u)) >> 16;
    return (unsigned short)r;
}
static __device__ __forceinline__ float bf2f(unsigned short h) {
    return __uint_as_float(((unsigned int)h) << 16);
}

// ---------------------------------------------------------------------------
// Kernel 1: per-batch GRU-like recurrence, LEVEL-PARALLEL.
// Dependency chains only run through repeat occurrences of the same user;
// lvl[t] = occurrence index of users[t]. All steps of one level are
// independent (distinct users) -> batch them in chunks of CH_=16 and compute
// block-matvecs with i-inner register accumulators (8 indep FMA chains per
// thread). Per-step arithmetic identical to the sequential version.
// 512 threads, 1 block per batch. LDS: state 128K + rbuf/zbuf 16K + misc.
// ---------------------------------------------------------------------------
__global__ __launch_bounds__(512) void rnn_kernel(
    const int*   __restrict__ users, const int* __restrict__ items,
    const float* __restrict__ h0,
    const float* __restrict__ P_ru, const float* __restrict__ W_ru,
    const float* __restrict__ b_ru,
    const float* __restrict__ P_c,  const float* __restrict__ W_c,
    const float* __restrict__ b_c,
    float* __restrict__ At)          // [H_][ROWS_] k-major
{
    __shared__ float state[U_ * H_];    // 128 KiB
    __shared__ float rbuf[CH_ * H_];    // 8 KiB  r*h_prev, premultiplied
    __shared__ float zbuf[CH_ * H_];    // 8 KiB
    __shared__ int   us[S_];
    __shared__ int   is[S_];
    __shared__ int   lvl_s[S_];
    __shared__ int   cnt_s[S_];
    __shared__ int   fill_s[S_];
    __shared__ int   lstart_s[S_ + 1];
    __shared__ unsigned char order_s[S_];
    __shared__ int   nlev_s;

    const int b   = blockIdx.x;
    const int tid = threadIdx.x;

    // init state from h0 (coalesced float4 copy: 32768 floats / 512 thr)
    {
        const float4* src = (const float4*)(h0 + (size_t)b * U_ * H_);
        float4*       dst = (float4*)state;
        #pragma unroll
        for (int i = 0; i < (U_ * H_ / 4) / 512; ++i)
            dst[i * 512 + tid] = src[i * 512 + tid];
    }
    if (tid < S_) {
        us[tid]     = users[b * S_ + tid];
        is[tid]     = items[b * S_ + tid];
        cnt_s[tid]  = 0;
        fill_s[tid] = 0;
    }
    __syncthreads();

    // ---- dependency levels: lvl[t] = # prior occurrences of users[t] ----
    if (tid < S_) {
        const int u = us[tid];
        int c = 0;
        for (int t2 = 0; t2 < tid; ++t2) c += (us[t2] == u);
        lvl_s[tid] = c;
        atomicAdd(&cnt_s[c], 1);
    }
    __syncthreads();
    if (tid == 0) {
        int run = 0, nl = 0;
        for (int L = 0; L < S_; ++L) {
            lstart_s[L] = run;
            if (cnt_s[L]) nl = L + 1;
            run += cnt_s[L];
        }
        lstart_s[S_] = run;
        nlev_s = nl;
    }
    __syncthreads();
    if (tid < S_) {
        const int L = lvl_s[tid];
        const int p = atomicAdd(&fill_s[L], 1);
        order_s[lstart_s[L] + p] = (unsigned char)tid;
    }
    __syncthreads();

    const int nlev = nlev_s;

    // phase A thread mapping: 2 groups x 256 j-cols, 8 steps per group
    const int gA = tid >> 8;          // 0..1
    const int jA = tid & 255;
    const float brj = b_ru[jA];
    // phase B thread mapping: 4 groups x 128 j-cols, 4 steps per group
    const int gB = tid >> 7;          // 0..3
    const int jB = tid & 127;
    const float bcj = b_c[jB];

    for (int L = 0; L < nlev; ++L) {
        const int s0 = lstart_s[L];
        const int n  = lstart_s[L + 1] - s0;
        for (int c0 = 0; c0 < n; c0 += CH_) {
            const int cn = min(CH_, n - c0);

            // ---------------- Phase A: ru[i][jA], i in [0,cn) ----------------
            {
                const float* hb[8];
                int sit[8];
                #pragma unroll
                for (int ii = 0; ii < 8; ++ii) {
                    const int i = gA * 8 + ii;
                    const int t = (i < cn) ? (int)order_s[s0 + c0 + i] : 0;
                    const int u = (i < cn) ? us[t] : 0;
                    sit[ii] = (i < cn) ? is[t] : 0;
                    hb[ii]  = state + u * H_;
                }
                float p[8];
                #pragma unroll
                for (int ii = 0; ii < 8; ++ii)
                    p[ii] = P_ru[(size_t)sit[ii] * H2_ + jA];

                float acc[8] = {0.f,0.f,0.f,0.f,0.f,0.f,0.f,0.f};
                #pragma unroll 4
                for (int k4 = 0; k4 < 32; ++k4) {
                    const int kb = k4 * 4;
                    const float w0 = W_ru[(kb + 0) * H2_ + jA];
                    const float w1 = W_ru[(kb + 1) * H2_ + jA];
                    const float w2 = W_ru[(kb + 2) * H2_ + jA];
                    const float w3 = W_ru[(kb + 3) * H2_ + jA];
                    #pragma unroll
                    for (int ii = 0; ii < 8; ++ii) {
                        const float4 hv = *((const float4*)(hb[ii] + kb));
                        acc[ii] = fmaf(hv.x, w0, acc[ii]);
                        acc[ii] = fmaf(hv.y, w1, acc[ii]);
                        acc[ii] = fmaf(hv.z, w2, acc[ii]);
                        acc[ii] = fmaf(hv.w, w3, acc[ii]);
                    }
                }
                #pragma unroll
                for (int ii = 0; ii < 8; ++ii) {
                    const int i = gA * 8 + ii;
                    if (i < cn) {
                        const float a  = acc[ii] + p[ii] + brj;
                        const float sg = 1.f / (1.f + expf(-a));
                        if (jA < H_) rbuf[i * H_ + jA] = sg * hb[ii][jA];
                        else         zbuf[i * H_ + (jA - H_)] = sg;
                    }
                }
            }
            __syncthreads();

            // ---------------- Phase B: c/h_new[i][jB] ----------------
            {
                const float* rb[4];
                int sit2[4], su2[4], stp2[4];
                #pragma unroll
                for (int ii = 0; ii < 4; ++ii) {
                    const int i = gB * 4 + ii;
                    const int t = (i < cn) ? (int)order_s[s0 + c0 + i] : 0;
                    stp2[ii] = t;
                    su2[ii]  = (i < cn) ? us[t] : 0;
                    sit2[ii] = (i < cn) ? is[t] : 0;
                    rb[ii]   = rbuf + ((i < cn) ? i : 0) * H_;
                }
                float pc[4];
                #pragma unroll
                for (int ii = 0; ii < 4; ++ii)
                    pc[ii] = P_c[(size_t)sit2[ii] * H_ + jB];

                float acc2[4] = {0.f,0.f,0.f,0.f};
                #pragma unroll 4
                for (int k4 = 0; k4 < 32; ++k4) {
                    const int kb = k4 * 4;
                    const float w0 = W_c[(kb + 0) * H_ + jB];
                    const float w1 = W_c[(kb + 1) * H_ + jB];
                    const float w2 = W_c[(kb + 2) * H_ + jB];
                    const float w3 = W_c[(kb + 3) * H_ + jB];
                    #pragma unroll
                    for (int ii = 0; ii < 4; ++ii) {
                        const float4 rv = *((const float4*)(rb[ii] + kb));
                        acc2[ii] = fmaf(rv.x, w0, acc2[ii]);
                        acc2[ii] = fmaf(rv.y, w1, acc2[ii]);
                        acc2[ii] = fmaf(rv.z, w2, acc2[ii]);
                        acc2[ii] = fmaf(rv.w, w3, acc2[ii]);
                    }
                }
                #pragma unroll
                for (int ii = 0; ii < 4; ++ii) {
                    const int i = gB * 4 + ii;
                    if (i < cn) {
                        const float cv = tanhf(acc2[ii] + pc[ii] + bcj);
                        const float z  = zbuf[i * H_ + jB];
                        const float hp = state[su2[ii] * H_ + jB];
                        const float hn = fmaf(z, hp - cv, cv);
                        state[su2[ii] * H_ + jB] = hn;
                        At[(size_t)jB * ROWS_ + b * S_ + stp2[ii]] = hn;
                    }
                }
            }
            __syncthreads();
        }
    }
}

// ---------------------------------------------------------------------------
// Kernel 2a: pack A' = [A_hi | A_lo | A_hi] into MFMA fragment order.
// ---------------------------------------------------------------------------
__global__ __launch_bounds__(256) void convA_kernel(
    const float* __restrict__ At, short* __restrict__ Ap)
{
    const int gidx = blockIdx.x * 256 + threadIdx.x;   // [0, 12*256*64)
    const int lane = gidx & 63;
    const int tile = gidx >> 6;        // k32*256 + r16
    const int k32  = tile >> 8;
    const int r16  = tile & 255;
    const int part = k32 >> 2;
    const int ks   = (k32 & 3) * 32 + (lane >> 4) * 8;  // source k in [0,128)
    const int row  = r16 * 16 + (lane & 15);
    short8 v;
    #pragma unroll
    for (int j = 0; j < 8; ++j) {
        const float x = At[(size_t)(ks + j) * ROWS_ + row];
        const unsigned short hi = f2bf(x);
        v[j] = (short)((part == 1) ? f2bf(x - bf2f(hi)) : hi);
    }
    *(short8*)(Ap + (size_t)gidx * 8) = v;
}

// ---------------------------------------------------------------------------
// Kernel 2b: pack B' = [B_hi ; B_hi ; B_lo] the same way.
// ---------------------------------------------------------------------------
__global__ __launch_bounds__(256) void convB_kernel(
    const float* __restrict__ wsm, short* __restrict__ Bp)
{
    const int gidx = blockIdx.x * 256 + threadIdx.x;   // [0, 12*1880*64)
    const int lane = gidx & 63;
    const int tile = gidx >> 6;        // k32*1880 + c16
    const int k32  = tile / NC16_;
    const int c16  = tile - k32 * NC16_;
    const int part = k32 >> 2;
    const int ks   = (k32 & 3) * 32 + (lane >> 4) * 8;
    const int col  = c16 * 16 + (lane & 15);
    short8 v;
    if (col < V_) {
        #pragma unroll
        for (int j = 0; j < 8; ++j) {
            const float x = wsm[(size_t)(ks + j) * V_ + col];
            const unsigned short hi = f2bf(x);
            v[j] = (short)((part == 2) ? f2bf(x - bf2f(hi)) : hi);
        }
    } else {
        #pragma unroll
        for (int j = 0; j < 8; ++j) v[j] = 0;
    }
    *(short8*)(Bp + (size_t)gidx * 8) = v;
}

// ---------------------------------------------------------------------------
// Kernel 3: MFMA GEMM  out[4096][30001] = A'[4096][384] @ B'[384][30001].
// ---------------------------------------------------------------------------
__global__ __launch_bounds__(256) void gemm_mfma_kernel(
    const short* __restrict__ Ap, const short* __restrict__ Bp,
    float* __restrict__ out)
{
    __shared__ short lsA[2][4096];   // [k32 sub][8 r16-tiles][64 lanes][8]
    __shared__ short lsB[2][4096];   // [k32 sub][8 c16-tiles][64 lanes][8]

    const int tid  = threadIdx.x;
    const int lane = tid & 63;
    const int wid  = tid >> 6;
    const int wr   = wid >> 1;       // wave row 0..1 (64-row slab)
    const int wc   = wid & 1;        // wave col 0..1 (64-col slab)
    const int rb16 = blockIdx.x * 8; // base row-16-tile
    const int cb16 = blockIdx.y * 8; // base col-16-tile

    const f32x4 zero = {0.f, 0.f, 0.f, 0.f};
    f32x4 acc[4][4];
    #pragma unroll
    for (int m = 0; m < 4; ++m)
        #pragma unroll
        for (int n = 0; n < 4; ++n) acc[m][n] = zero;

    for (int kk = 0; kk < 6; ++kk) {
        #pragma unroll
        for (int s = 0; s < 2; ++s) {
            const int k32 = kk * 2 + s;
            const short* ga = Ap + ((size_t)k32 * NR16_ + rb16) * 512;
            const short* gb = Bp + ((size_t)k32 * NC16_ + cb16) * 512;
            #pragma unroll
            for (int i = 0; i < 2; ++i) {
                const int idx = (i * 256 + tid) * 8;   // 16B per thread
                __builtin_amdgcn_global_load_lds(
                    (__attribute__((address_space(1))) void*)(ga + idx),
                    (__attribute__((address_space(3))) void*)(&lsA[s][idx]), 16, 0, 0);
                __builtin_amdgcn_global_load_lds(
                    (__attribute__((address_space(1))) void*)(gb + idx),
                    (__attribute__((address_space(3))) void*)(&lsB[s][idx]), 16, 0, 0);
            }
        }
        __syncthreads();

        #pragma unroll
        for (int s = 0; s < 2; ++s) {
            short8 a[4], b[4];
            #pragma unroll
            for (int m = 0; m < 4; ++m)
                a[m] = *(const short8*)&lsA[s][((wr * 4 + m) * 64 + lane) * 8];
            #pragma unroll
            for (int n = 0; n < 4; ++n)
                b[n] = *(const short8*)&lsB[s][((wc * 4 + n) * 64 + lane) * 8];
            #pragma unroll
            for (int m = 0; m < 4; ++m)
                #pragma unroll
                for (int n = 0; n < 4; ++n)
                    acc[m][n] = __builtin_amdgcn_mfma_f32_16x16x32_bf16(
                        a[m], b[n], acc[m][n], 0, 0, 0);
        }
        __syncthreads();
    }

    // Epilogue: C/D layout col = lane&15, row = (lane>>4)*4 + reg
    const int row0 = blockIdx.x * 128 + wr * 64 + ((lane >> 4) << 2);
    const int col0 = blockIdx.y * 128 + wc * 64 + (lane & 15);
    #pragma unroll
    for (int m = 0; m < 4; ++m) {
        #pragma unroll
        for (int n = 0; n < 4; ++n) {
            const int col = col0 + n * 16;
            if (col < V_) {
                float* o = out + (size_t)(row0 + m * 16) * V_ + col;
                o[0]              = acc[m][n][0];
                o[(size_t)V_]     = acc[m][n][1];
                o[(size_t)V_ * 2] = acc[m][n][2];
                o[(size_t)V_ * 3] = acc[m][n][3];
            }
        }
    }
}

extern "C" void kernel_launch(void* const* d_in, const int* in_sizes, int n_in,
                              void* d_out, int out_size, void* d_ws, size_t ws_size,
                              hipStream_t stream) {
    const int*   users = (const int*)  d_in[0];
    const int*   items = (const int*)  d_in[1];
    const float* h0    = (const float*)d_in[2];
    const float* P_ru  = (const float*)d_in[3];
    const float* W_ru  = (const float*)d_in[4];
    const float* b_ru  = (const float*)d_in[5];
    const float* P_c   = (const float*)d_in[6];
    const float* W_c   = (const float*)d_in[7];
    const float* b_c   = (const float*)d_in[8];
    const float* wsm   = (const float*)d_in[9];
    float* out = (float*)d_out;

    // workspace layout: At (2 MiB fp32) | Ap (3 MiB bf16) | Bp (22 MiB bf16)
    float* At = (float*)d_ws;                                        // [128][4096]
    short* Ap = (short*)((char*)d_ws + (size_t)2 * 1024 * 1024);     // 12*256*512
    short* Bp = (short*)((char*)d_ws + (size_t)2 * 1024 * 1024
                                     + (size_t)NK32_ * NR16_ * 512 * sizeof(short));

    rnn_kernel<<<B_, 512, 0, stream>>>(users, items, h0, P_ru, W_ru, b_ru,
                                       P_c, W_c, b_c, At);
    convA_kernel<<<(NK32_ * NR16_ * 64) / 256, 256, 0, stream>>>(At, Ap);
    convB_kernel<<<(NK32_ * NC16_ * 64) / 256, 256, 0, stream>>>(wsm, Bp);
    gemm_mfma_kernel<<<dim3(32, NCB_), 256, 0, stream>>>(Ap, Bp, out);
}